// Round 9
// baseline (184.651 us; speedup 1.0000x reference)
//
#include <hip/hip_runtime.h>

// B=64, K=8, H=W=128 (HW=16384). float32 in/out.
// out[0] = loss scalar; out[1..] = pred_perm (B,K,H,W) flat.
//
// SINGLE dispatch, 512 blocks x 256 threads, all co-resident by construction
// (__launch_bounds__(256,2): VGPR<=128, LDS ~3KB -> 2 blocks/CU x 256 CUs).
// Cooperative launch is broken in this harness (r6); instead we use the
// r7-PROVEN epoch-counter + threadfence pattern, extended with a per-batch
// ready-spin:
//   phase 1 (cost): block p=(i=p>>6, b=p&63): ONE pred row + 8 aug rows,
//       EXPLICITLY BATCHED loads (a[0..7] + sched_barrier) to avoid r8's
//       VGPR=28 load serialization. p===b (mod 64) keeps a batch's 8 blocks
//       on one XCD (r8-verified: FETCH=33MB, aug re-reads are cache-hits).
//       Epilogue: verified reduce-scatter -> g_part[p][9].
//   phase 2 (DP): 8th arrival of batch b (epoch counter g_cnt[b], &7 trick)
//       reduces 8x9 partials, runs verified Held-Karp DP -> g_invtab[b],
//       g_loss[b]; threadfence; bumps g_done[b] and g_all.
//   phase 3 (copy): every block spins (tid0 + s_sleep) until g_done[b] > E,
//       then copies out row (b, i) from pred row g_invtab[b][i] (verified
//       float4 copy). Block 0 finally waits g_all == 64*(E+1) and single-writes
//       out[0] (no atomics on out, no zero-init hazard, replay-safe).
// Why fuse: r8 counters proved the ~40us cost wall is the poison-fill's
// 268MB L3->HBM write drain (invisible to TCC) -- CU-side structure cannot
// beat it, but copy work can OVERLAP it per-batch, and one launch gap +
// permute startup disappear.

#define BB 64
#define KK 8
#define HW 16384
#define EPSF 1e-15f

// ---------- compile-time mask table: all 255 nonzero 8-bit masks, level-ordered by popcount ----------
struct MaskTab {
    unsigned char masks[255];
    int off[9];
};

constexpr MaskTab make_tab() {
    MaskTab t{};
    int idx = 0;
    for (int p = 1; p <= 8; ++p) {
        t.off[p - 1] = idx;
        for (int m = 1; m < 256; ++m) {
            int c = 0;
            for (int b = 0; b < 8; ++b) c += (m >> b) & 1;
            if (c == p) t.masks[idx++] = (unsigned char)m;
        }
    }
    t.off[8] = idx;
    return t;
}

__constant__ MaskTab kTab = make_tab();

// Persistent device state (zero-init .bss; epoch logic means NO resets needed --
// correct across warm-up, graph replays, and rocprof passes; r7-proven pattern).
__device__ int   g_cnt[64];     // +8 per launch per batch; (old&7)==7 marks DP block
__device__ int   g_done[64];    // +1 per launch per batch, after DP results visible
__device__ int   g_all;         // +64 per launch
__device__ float g_part[512 * 9];
__device__ float g_loss[64];
__device__ int   g_invtab[64][8];

__device__ __forceinline__ float dot4(float4 t, float4 l) {
    return t.x * l.x + t.y * l.y + t.z * l.z + t.w * l.w;
}

__device__ __forceinline__ float4 log4(float4 a) {
    float4 r;
    r.x = __logf(a.x + EPSF); r.y = __logf(a.y + EPSF);
    r.z = __logf(a.z + EPSF); r.w = __logf(a.w + EPSF);
    return r;
}

__global__ __launch_bounds__(256, 2) void fused_kernel(const float* __restrict__ pred,
                                                       const float* __restrict__ aug,
                                                       float* __restrict__ out)
{
    __shared__ float red[4][9];
    __shared__ int   sE, sLast;
    __shared__ float C[64];
    __shared__ float dp[256];
    __shared__ int   choice[256];

    const int p    = blockIdx.x;
    const int i    = p >> 6;        // pred row index 0..7
    const int b    = p & 63;        // batch; p === b (mod 64) -> same-XCD cluster
    const int tid  = threadIdx.x;
    const int wave = tid >> 6;
    const int lane = tid & 63;

    // ================= phase 1: cost partials (i-split, batched loads) =================
    const float* prow  = pred + ((size_t)b * KK + i) * HW;
    const float* abase = aug  + (size_t)b * KK * HW;

    float acc[8];
#pragma unroll
    for (int j = 0; j < 8; ++j) acc[j] = 0.f;
    float eacc = 0.f;

    const int rot = b & 15;         // per-batch phase rotation (batch-uniform: preserves reuse)

    for (int m = 0; m < 16; ++m) {
        const int mm = (m + rot) & 15;
        const int e  = (tid + 256 * mm) * 4;    // float offset within the row

        // batched load phase: 9 independent dwordx4, nothing else live
        const float4 pq = *(const float4*)(prow + e);
        float4 a[8];
#pragma unroll
        for (int j = 0; j < 8; ++j)
            a[j] = *(const float4*)(abase + (size_t)j * HW + e);
        __builtin_amdgcn_sched_barrier(0);      // pin: all loads issued before compute

        const float4 la = log4(pq);
#pragma unroll
        for (int j = 0; j < 8; ++j) {
            acc[j] += dot4(a[j], la);
            if (j == i) eacc += dot4(a[j], log4(a[j]));   // block-uniform branch; static a[j] index
        }
    }

    // --- 3-round reduce-scatter over acc[8] (r8-verified) ---
#pragma unroll
    for (int r = 0; r < 3; ++r) {
        const int d    = 1 << r;
        const int half = 4 >> r;
        const bool hi  = (lane & d) != 0;
#pragma unroll
        for (int k = 0; k < half; ++k) {
            const float send = hi ? acc[k] : acc[k + half];
            const float recv = __shfl_xor(send, d);
            acc[k] = (hi ? acc[k + half] : acc[k]) + recv;
        }
    }
    float av = acc[0];
    av += __shfl_xor(av, 8);
    av += __shfl_xor(av, 16);
    av += __shfl_xor(av, 32);
    // lane l holds cross_total[bitrev3(l & 7)]

#pragma unroll
    for (int d = 1; d < 64; d <<= 1) eacc += __shfl_xor(eacc, d);

    if (lane < 8)
        red[wave][((lane & 1) << 2) | (lane & 2) | ((lane & 4) >> 2)] = av;
    if (lane == 0)
        red[wave][8] = eacc;
    __syncthreads();

    if (tid < 9)
        g_part[(size_t)p * 9 + tid] = red[0][tid] + red[1][tid] + red[2][tid] + red[3][tid];
    __threadfence();                 // release: partials device-visible before counter bump
    __syncthreads();

    if (tid == 0) {
        const int old = atomicAdd(&g_cnt[b], 1);
        sLast = ((old & 7) == 7);    // 8th arrival of THIS launch (epoch trick)
        sE    = old >> 3;            // launch epoch for this batch
    }
    __syncthreads();

    // ================= phase 2: DP by the last-arriving block of batch b =================
    if (sLast) {
        __threadfence();             // acquire: peers' partials visible (r7-proven)

        if (tid < 64) {
            const int ii = tid >> 3, jj = tid & 7;
            const float cross = g_part[((size_t)ii * 64 + b) * 9 + jj];
            const float entj  = g_part[((size_t)jj * 64 + b) * 9 + 8];
            C[tid] = entj - cross;
        }
        if (tid == 0) dp[0] = 0.f;
        __syncthreads();

        const int grp = tid >> 3;
        const int j   = tid & 7;
        for (int lvl = 1; lvl <= 8; ++lvl) {
            const int start = kTab.off[lvl - 1];
            const int end   = kTab.off[lvl];
            const float* Crow = &C[(lvl - 1) * 8];
            for (int bse = start; bse < end; bse += 32) {
                const int mi = bse + grp;
                if (mi < end) {
                    const int M = kTab.masks[mi];
                    float v  = 1e30f;
                    int   bj = 0;
                    if (M & (1 << j)) {
                        v  = dp[M ^ (1 << j)] + Crow[j];
                        bj = j;
                    }
#pragma unroll
                    for (int d = 1; d < 8; d <<= 1) {
                        const float ov = __shfl_xor(v, d);
                        const int   oj = __shfl_xor(bj, d);
                        if (ov < v) { v = ov; bj = oj; }
                    }
                    if (j == 0) { dp[M] = v; choice[M] = bj; }
                }
            }
            __syncthreads();
        }

        if (tid == 0) {
            int mask = 255;
            for (int r = 7; r >= 0; --r) {
                const int jj = choice[mask];
                g_invtab[b][jj] = r;     // column jj takes pred row r
                mask ^= 1 << jj;
            }
            g_loss[b] = dp[255];
            __threadfence();             // release: invtab/loss visible before ready bump
            atomicAdd(&g_done[b], 1);
            atomicAdd(&g_all, 1);
        }
        __syncthreads();
    }

    // ================= phase 3: spin until batch ready, then permuted copy =================
    if (tid == 0) {
        const int E = sE;
        while (atomicAdd(&g_done[b], 0) <= E)
            __builtin_amdgcn_s_sleep(16);
    }
    __syncthreads();
    __threadfence();                 // acquire: invtab visible to all lanes

    const int src_row = g_invtab[b][i];   // uniform per block
    const float* src  = pred + ((size_t)(b << 3) + src_row) * HW;
    float*      drow  = out + 1 + ((size_t)(b << 3) + i) * HW;

#pragma unroll
    for (int m = 0; m < 16; ++m) {
        const int f = tid + 256 * m;              // quad index in [0,4096)
        const int e = 3 + 4 * f;
        if (f < 4095) {
            float4 v;
            v.x = src[e]; v.y = src[e + 1]; v.z = src[e + 2]; v.w = src[e + 3];
            *(float4*)(drow + e) = v;             // 16B-aligned
        } else {                                  // f==4095: head 3 + tail 1
            drow[0] = src[0]; drow[1] = src[1]; drow[2] = src[2];
            drow[16383] = src[16383];
        }
    }

    // --- block 0: wait for all batches, single-writer loss (replay-safe, no atomics on out) ---
    if (p == 0) {
        if (tid == 0) {
            const int target = 64 * (sE + 1);
            while (atomicAdd(&g_all, 0) < target)
                __builtin_amdgcn_s_sleep(16);
        }
        __syncthreads();
        __threadfence();
        if (tid < 64) {
            float lv = g_loss[tid];
#pragma unroll
            for (int d = 1; d < 64; d <<= 1) lv += __shfl_xor(lv, d);
            if (tid == 0) out[0] = lv * (1.0f / (16384.0f * 512.0f));
        }
    }
}

extern "C" void kernel_launch(void* const* d_in, const int* in_sizes, int n_in,
                              void* d_out, int out_size, void* d_ws, size_t ws_size,
                              hipStream_t stream) {
    const float* pred = (const float*)d_in[0];
    const float* aug  = (const float*)d_in[1];
    float* out = (float*)d_out;

    fused_kernel<<<dim3(512), dim3(256), 0, stream>>>(pred, aug, out);
}